// Round 13
// baseline (81.734 us; speedup 1.0000x reference)
//
#include <hip/hip_runtime.h>

#define GCN_N 100000
#define GCN_E 3200000
#define GCN_C 256
#define BSHIFT 8
#define NBUCK 391            // ceil(N/256)
#define BCAP 9216            // mean fill 8184, sigma ~90 -> >11 sigma headroom

#define NBIN 1024            // bin blocks (4/CU at ~31.5KB LDS)
#define TBB 512              // bin threads/block
#define CHUNK (GCN_E / NBIN) // 3125 edges/block (exact)

// K1: h[i] = dot(x[i,:],W) (one wave/node, proven BW-bound ~16us).
// Block 0 additionally zeroes the cursor for this call (runs before k_bin).
__global__ void k_proj_init(const float* __restrict__ x, const float* __restrict__ W,
                            float* __restrict__ h, int* __restrict__ cursor, int n) {
    if (blockIdx.x == 0) {
        for (int i = threadIdx.x; i < NBUCK; i += blockDim.x) cursor[i] = 0;
    }
    const int lane   = threadIdx.x & 63;
    const int wave   = (blockIdx.x * blockDim.x + threadIdx.x) >> 6;
    const int nwaves = (gridDim.x * blockDim.x) >> 6;
    const float4 wf = *reinterpret_cast<const float4*>(W + lane * 4);
    for (int i = wave; i < n; i += nwaves) {
        const float4 xv = *reinterpret_cast<const float4*>(x + (size_t)i * GCN_C + lane * 4);
        float s = xv.x * wf.x + xv.y * wf.y + xv.z * wf.z + xv.w * wf.w;
        #pragma unroll
        for (int off = 32; off > 0; off >>= 1)
            s += __shfl_down(s, off, 64);
        if (lane == 0) h[i] = s;
    }
}

// K2: counting-sort bin, 2-copy histograms (wave-parity) to halve same-address
// LDS atomic serialization in BOTH passes; no per-thread arrays; staged sort;
// coalesced-run flush. ~31.5KB LDS -> 4 blocks/CU.
__global__ void __launch_bounds__(TBB) k_bin(const int* __restrict__ src,
                                             const int* __restrict__ dst,
                                             int* __restrict__ cursor,
                                             int* __restrict__ bpack) {
    __shared__ int hist0[NBUCK], hist1[NBUCK];   // copy counters -> copy cursors
    __shared__ int scan0[NBUCK];                 // frozen exclusive scan (local)
    __shared__ int gbase[NBUCK];                 // global in-bucket base (0-based)
    __shared__ int wsum[8], woff[8];
    __shared__ int spack[CHUNK];
    __shared__ int sdest[CHUNK];
    const int tid = threadIdx.x, blk = blockIdx.x;
    const int lane = tid & 63, wv = tid >> 6;
    const int myc = wv & 1;                      // histogram copy id

    for (int b = tid; b < NBUCK; b += TBB) { hist0[b] = 0; hist1[b] = 0; }
    __syncthreads();

    // ---- A: histogram into per-parity copies (count-only LDS atomics) ----
    const int c0 = blk * CHUNK;
    int* myh = myc ? hist1 : hist0;
    for (int k = tid; k < CHUNK; k += TBB)
        atomicAdd(&myh[dst[c0 + k] >> BSHIFT], 1);
    __syncthreads();

    // ---- B: merge + global reservation + wave-scan; seed copy cursors ----
    int v = 0;
    if (tid < NBUCK) {
        v = hist0[tid] + hist1[tid];
        gbase[tid] = atomicAdd(&cursor[tid], v);   // hides under the scan below
    }
    {
        int incl = v;
        #pragma unroll
        for (int d2 = 1; d2 < 64; d2 <<= 1) {
            const int t = __shfl_up(incl, d2, 64);
            if (lane >= d2) incl += t;
        }
        if (lane == 63) wsum[wv < 8 ? wv : 7] = incl;   // waves 0..6 used
        __syncthreads();
        if (tid == 0) { int s = 0; for (int k2 = 0; k2 < 8; ++k2) { woff[k2] = s; s += wsum[k2]; } }
        __syncthreads();
        if (tid < NBUCK) {
            const int e = incl - v + woff[wv];          // exclusive scan
            scan0[tid] = e;
            const int h0 = hist0[tid];
            hist1[tid] = e + h0;                        // copy-1 cursor start
            hist0[tid] = e;                             // copy-0 cursor start
        }
    }
    __syncthreads();

    // ---- C: re-read (L2-hot), place via per-copy LDS cursors ----
    int* mycur = myc ? hist1 : hist0;
    for (int k = tid; k < CHUNK; k += TBB) {
        const int d = dst[c0 + k];
        const int s = src[c0 + k];
        const int b = d >> BSHIFT;
        const int slot = atomicAdd(&mycur[b], 1);            // LDS ret (2 copies)
        const int goff = gbase[b] + (slot - scan0[b]);       // in-bucket offset
        spack[slot] = (s << BSHIFT) | (d & 255);
        sdest[slot] = (goff < BCAP) ? (b * BCAP + goff) : -1;  // overflow guard
    }
    __syncthreads();

    // ---- D: coalesced-run flush ----
    for (int i = tid; i < CHUNK; i += TBB) {
        const int dpos = sdest[i];
        if (dpos >= 0) bpack[dpos] = spack[i];
    }
}

// K3: degree per node from bucket p; dis = rsqrt(1+deg); g = dis*h.
__global__ void __launch_bounds__(1024) k_deg_norm(const int* __restrict__ bpack,
                                                   const int* __restrict__ cursor,
                                                   const float* __restrict__ h,
                                                   float* __restrict__ dis,
                                                   float* __restrict__ g) {
    __shared__ int cnt[256];
    const int p = blockIdx.x, tid = threadIdx.x;
    if (tid < 256) cnt[tid] = 0;
    __syncthreads();
    const int s0 = p * BCAP, s1 = s0 + min(cursor[p], BCAP);
    for (int i = s0 + tid; i < s1; i += 1024)
        atomicAdd(&cnt[bpack[i] & 255], 1);
    __syncthreads();
    if (tid < 256) {
        const int node = (p << BSHIFT) + tid;
        if (node < GCN_N) {
            const float r = rsqrtf(1.0f + (float)cnt[tid]);    // +1 self-loop
            dis[node] = r;
            g[node]   = r * h[node];
        }
    }
}

// K4: acc[dst&255] += g[src] over bucket p; out = b + dis*(acc + g_self).
__global__ void __launch_bounds__(1024) k_scatter_bin(const int* __restrict__ bpack,
                                                      const int* __restrict__ cursor,
                                                      const float* __restrict__ g,
                                                      const float* __restrict__ dis,
                                                      const float* __restrict__ bias,
                                                      float* __restrict__ out) {
    __shared__ float acc[256];
    const int p = blockIdx.x, tid = threadIdx.x;
    if (tid < 256) acc[tid] = 0.0f;
    __syncthreads();
    const int s0 = p * BCAP, s1 = s0 + min(cursor[p], BCAP);
    for (int i = s0 + tid; i < s1; i += 1024) {
        const int pk = bpack[i];
        atomicAdd(&acc[pk & 255], g[pk >> BSHIFT]);            // LDS f32
    }
    __syncthreads();
    if (tid < 256) {
        const int node = (p << BSHIFT) + tid;
        if (node < GCN_N)
            out[node] = bias[0] + dis[node] * (acc[tid] + g[node]);
    }
}

// ---------- fallback: scattered global atomics (known-good) ----------
__global__ void k_zero(float* __restrict__ a, int n) {
    int i = blockIdx.x * blockDim.x + threadIdx.x;
    const int stride = gridDim.x * blockDim.x;
    for (; i < n; i += stride) a[i] = 0.0f;
}
__global__ void k_proj_sep(const float* __restrict__ x, const float* __restrict__ W,
                           float* __restrict__ h, int n) {
    const int lane   = threadIdx.x & 63;
    const int wave   = (blockIdx.x * blockDim.x + threadIdx.x) >> 6;
    const int nwaves = (gridDim.x * blockDim.x) >> 6;
    const float4 wf = *reinterpret_cast<const float4*>(W + lane * 4);
    for (int i = wave; i < n; i += nwaves) {
        const float4 xv = *reinterpret_cast<const float4*>(x + (size_t)i * GCN_C + lane * 4);
        float s = xv.x * wf.x + xv.y * wf.y + xv.z * wf.z + xv.w * wf.w;
        #pragma unroll
        for (int off = 32; off > 0; off >>= 1)
            s += __shfl_down(s, off, 64);
        if (lane == 0) h[i] = s;
    }
}
__global__ void k_degree_flat(const int* __restrict__ dst, float* __restrict__ deg, int e) {
    int i = blockIdx.x * blockDim.x + threadIdx.x;
    const int stride = gridDim.x * blockDim.x;
    for (; i < e; i += stride) atomicAdd(&deg[dst[i]], 1.0f);
}
__global__ void k_norm_flat(const float* __restrict__ h, float* __restrict__ deg_dis,
                            float* __restrict__ out, const float* __restrict__ bias, int n) {
    const int i = blockIdx.x * blockDim.x + threadIdx.x;
    if (i < n) {
        const float r = rsqrtf(deg_dis[i] + 1.0f);
        deg_dis[i] = r;
        out[i] = bias[0] + r * r * h[i];
    }
}
__global__ void k_scatter_flat(const int* __restrict__ src, const int* __restrict__ dst,
                               const float* __restrict__ h, const float* __restrict__ dis,
                               float* __restrict__ out, int e) {
    int i = blockIdx.x * blockDim.x + threadIdx.x;
    const int stride = gridDim.x * blockDim.x;
    for (; i < e; i += stride) {
        const int s = src[i], d = dst[i];
        atomicAdd(&out[d], dis[s] * dis[d] * h[s]);
    }
}

extern "C" void kernel_launch(void* const* d_in, const int* in_sizes, int n_in,
                              void* d_out, int out_size, void* d_ws, size_t ws_size,
                              hipStream_t stream) {
    const float* x  = (const float*)d_in[0];
    const int*   ei = (const int*)d_in[1];     // [2,E] int32: src row, dst row
    const float* W  = (const float*)d_in[2];
    const float* b  = (const float*)d_in[3];
    float* out = (float*)d_out;
    const int* src = ei;
    const int* dst = ei + GCN_E;

    float* h      = (float*)d_ws;                        // N
    float* dis    = h + GCN_N;                           // N
    float* g      = dis + GCN_N;                         // N
    int*   cursor = (int*)(g + GCN_N);                   // NBUCK
    int*   bpack  = cursor + NBUCK;                      // NBUCK*BCAP
    const size_t need = ((size_t)3 * GCN_N + NBUCK + (size_t)NBUCK * BCAP) * 4;

    if (ws_size >= need) {
        k_proj_init<<<2048, 256, 0, stream>>>(x, W, h, cursor, GCN_N);
        k_bin<<<NBIN, TBB, 0, stream>>>(src, dst, cursor, bpack);
        k_deg_norm<<<NBUCK, 1024, 0, stream>>>(bpack, cursor, h, dis, g);
        k_scatter_bin<<<NBUCK, 1024, 0, stream>>>(bpack, cursor, g, dis, b, out);
    } else {
        float* hh  = (float*)d_ws;
        float* deg = hh + GCN_N;
        k_zero<<<512, 256, 0, stream>>>(deg, GCN_N);
        k_proj_sep<<<2048, 256, 0, stream>>>(x, W, hh, GCN_N);
        k_degree_flat<<<2048, 256, 0, stream>>>(dst, deg, GCN_E);
        k_norm_flat<<<(GCN_N + 255) / 256, 256, 0, stream>>>(hh, deg, out, b, GCN_N);
        k_scatter_flat<<<2048, 256, 0, stream>>>(src, dst, hh, deg, out, GCN_E);
    }
}

// Round 15
// 68.120 us; speedup vs baseline: 1.1999x; 1.1999x over previous
//
#include <hip/hip_runtime.h>

#define GCN_N 100000
#define GCN_E 3200000
#define GCN_C 256
#define BSHIFT 8
#define NBUCK 391            // ceil(N/256)
#define BCAP 9216            // mean fill 8184, sigma ~90 -> >11 sigma headroom

#define NBLK 512             // fused blocks
#define TB 1024              // threads/block (16 waves)
#define CHUNK (GCN_E / NBLK) // 6250 edges/block (exact)
#define EPT ((CHUNK + TB - 1) / TB)        // 7 edge iters/thread (14 row slots)
#define ROWS ((GCN_N + NBLK - 1) / NBLK)   // 196 proj rows/block (needs <=13 slots/wave)

// K0: zero cursors (separate tiny dispatch: must complete before any reserve).
__global__ void k_init(int* __restrict__ cursor) {
    const int i = threadIdx.x;
    if (i < NBUCK) cursor[i] = 0;
}

// K1: fused bin+proj with INSTRUCTION-LEVEL interleave: each unrolled iter
// issues 2 proj x-row loads (VMEM, independent) + 1 edge intake (LDS
// atomic-ret), so bin's latency is hidden under proj's streaming loads.
__global__ void __launch_bounds__(TB) k_fused(const float* __restrict__ x,
                                              const float* __restrict__ W,
                                              float* __restrict__ h,
                                              const int* __restrict__ src,
                                              const int* __restrict__ dst,
                                              int* __restrict__ cursor,
                                              int* __restrict__ bpack) {
    __shared__ int hist[NBUCK];
    __shared__ int lscan[NBUCK];
    __shared__ int gbase[NBUCK];
    __shared__ int wsum[16], woff[16];
    __shared__ int spack[CHUNK];
    __shared__ int sdest[CHUNK];
    const int tid = threadIdx.x, blk = blockIdx.x;
    const int lane = tid & 63, wv = tid >> 6;

    for (int b = tid; b < NBUCK; b += TB) hist[b] = 0;
    __syncthreads();

    // ---- Phase 1: interleaved intake + projection ----
    const int c0 = blk * CHUNK;
    const int r0 = blk * ROWS;
    const int r1 = min(r0 + ROWS, GCN_N);
    const float4 wf = *reinterpret_cast<const float4*>(W + lane * 4);
    int my_pack[EPT], my_b[EPT], my_off[EPT];
    #pragma unroll
    for (int j = 0; j < EPT; ++j) {
        // proj row slots m=2j and m=2j+1 for this wave (14 slots >= 13 needed)
        const int ra = r0 + wv + 16 * (2 * j);
        const int rb = r0 + wv + 16 * (2 * j + 1);
        float4 xa, xb;
        const bool da = (ra < r1);
        const bool db = (rb < r1);
        if (da) xa = *reinterpret_cast<const float4*>(x + (size_t)ra * GCN_C + lane * 4);
        if (db) xb = *reinterpret_cast<const float4*>(x + (size_t)rb * GCN_C + lane * 4);

        // edge intake j (LDS atomic latency overlaps the x-row loads above)
        const int k = tid + j * TB;
        my_b[j] = -1;
        if (k < CHUNK) {
            const int d = dst[c0 + k];
            const int s = src[c0 + k];
            const int b = d >> BSHIFT;
            my_pack[j] = (s << BSHIFT) | (d & 255);
            my_b[j]    = b;
            my_off[j]  = atomicAdd(&hist[b], 1);
        }

        // finish proj rows (VALU shfl chains, independent of the atomic)
        if (da) {
            float s0 = xa.x * wf.x + xa.y * wf.y + xa.z * wf.z + xa.w * wf.w;
            #pragma unroll
            for (int off = 32; off > 0; off >>= 1) s0 += __shfl_down(s0, off, 64);
            if (lane == 0) h[ra] = s0;
        }
        if (db) {
            float s1 = xb.x * wf.x + xb.y * wf.y + xb.z * wf.z + xb.w * wf.w;
            #pragma unroll
            for (int off = 32; off > 0; off >>= 1) s1 += __shfl_down(s1, off, 64);
            if (lane == 0) h[rb] = s1;
        }
    }
    __syncthreads();

    // ---- Phase 2: global reservation (hides under scan) + wave-scan ----
    if (tid < NBUCK) gbase[tid] = atomicAdd(&cursor[tid], hist[tid]);
    {
        const int v = (tid < NBUCK) ? hist[tid] : 0;
        int incl = v;
        #pragma unroll
        for (int d2 = 1; d2 < 64; d2 <<= 1) {
            const int t = __shfl_up(incl, d2, 64);
            if (lane >= d2) incl += t;
        }
        if (lane == 63 && wv < 7) wsum[wv] = incl;
        __syncthreads();
        if (tid == 0) { int s = 0; for (int k2 = 0; k2 < 7; ++k2) { woff[k2] = s; s += wsum[k2]; } }
        __syncthreads();
        if (tid < NBUCK) lscan[tid] = incl - v + woff[wv];   // exclusive
    }
    __syncthreads();

    // ---- Phase 3: bucket-sorted LDS staging + global dest ----
    #pragma unroll
    for (int j = 0; j < EPT; ++j) {
        if (my_b[j] >= 0) {
            const int b    = my_b[j];
            const int slot = lscan[b] + my_off[j];
            const int goff = gbase[b] + my_off[j];
            spack[slot] = my_pack[j];
            sdest[slot] = (goff < BCAP) ? (b * BCAP + goff) : -1;  // overflow guard
        }
    }
    __syncthreads();

    // ---- Phase 4: coalesced-run flush ----
    for (int i = tid; i < CHUNK; i += TB) {
        const int dpos = sdest[i];
        if (dpos >= 0) bpack[dpos] = spack[i];
    }
}

// K2: degree per node from bucket p; dis = rsqrt(1+deg); g = dis*h.
__global__ void __launch_bounds__(1024) k_deg_norm(const int* __restrict__ bpack,
                                                   const int* __restrict__ cursor,
                                                   const float* __restrict__ h,
                                                   float* __restrict__ dis,
                                                   float* __restrict__ g) {
    __shared__ int cnt[256];
    const int p = blockIdx.x, tid = threadIdx.x;
    if (tid < 256) cnt[tid] = 0;
    __syncthreads();
    const int s0 = p * BCAP, s1 = s0 + min(cursor[p], BCAP);
    for (int i = s0 + tid; i < s1; i += 1024)
        atomicAdd(&cnt[bpack[i] & 255], 1);
    __syncthreads();
    if (tid < 256) {
        const int node = (p << BSHIFT) + tid;
        if (node < GCN_N) {
            const float r = rsqrtf(1.0f + (float)cnt[tid]);    // +1 self-loop
            dis[node] = r;
            g[node]   = r * h[node];
        }
    }
}

// K3: acc[dst&255] += g[src] over bucket p; out = b + dis*(acc + g_self).
__global__ void __launch_bounds__(1024) k_scatter_bin(const int* __restrict__ bpack,
                                                      const int* __restrict__ cursor,
                                                      const float* __restrict__ g,
                                                      const float* __restrict__ dis,
                                                      const float* __restrict__ bias,
                                                      float* __restrict__ out) {
    __shared__ float acc[256];
    const int p = blockIdx.x, tid = threadIdx.x;
    if (tid < 256) acc[tid] = 0.0f;
    __syncthreads();
    const int s0 = p * BCAP, s1 = s0 + min(cursor[p], BCAP);
    for (int i = s0 + tid; i < s1; i += 1024) {
        const int pk = bpack[i];
        atomicAdd(&acc[pk & 255], g[pk >> BSHIFT]);            // LDS f32
    }
    __syncthreads();
    if (tid < 256) {
        const int node = (p << BSHIFT) + tid;
        if (node < GCN_N)
            out[node] = bias[0] + dis[node] * (acc[tid] + g[node]);
    }
}

// ---------- fallback: scattered global atomics (known-good) ----------
__global__ void k_zero(float* __restrict__ a, int n) {
    int i = blockIdx.x * blockDim.x + threadIdx.x;
    const int stride = gridDim.x * blockDim.x;
    for (; i < n; i += stride) a[i] = 0.0f;
}
__global__ void k_proj_sep(const float* __restrict__ x, const float* __restrict__ W,
                           float* __restrict__ h, int n) {
    const int lane   = threadIdx.x & 63;
    const int wave   = (blockIdx.x * blockDim.x + threadIdx.x) >> 6;
    const int nwaves = (gridDim.x * blockDim.x) >> 6;
    const float4 wf = *reinterpret_cast<const float4*>(W + lane * 4);
    for (int i = wave; i < n; i += nwaves) {
        const float4 xv = *reinterpret_cast<const float4*>(x + (size_t)i * GCN_C + lane * 4);
        float s = xv.x * wf.x + xv.y * wf.y + xv.z * wf.z + xv.w * wf.w;
        #pragma unroll
        for (int off = 32; off > 0; off >>= 1)
            s += __shfl_down(s, off, 64);
        if (lane == 0) h[i] = s;
    }
}
__global__ void k_degree_flat(const int* __restrict__ dst, float* __restrict__ deg, int e) {
    int i = blockIdx.x * blockDim.x + threadIdx.x;
    const int stride = gridDim.x * blockDim.x;
    for (; i < e; i += stride) atomicAdd(&deg[dst[i]], 1.0f);
}
__global__ void k_norm_flat(const float* __restrict__ h, float* __restrict__ deg_dis,
                            float* __restrict__ out, const float* __restrict__ bias, int n) {
    const int i = blockIdx.x * blockDim.x + threadIdx.x;
    if (i < n) {
        const float r = rsqrtf(deg_dis[i] + 1.0f);
        deg_dis[i] = r;
        out[i] = bias[0] + r * r * h[i];
    }
}
__global__ void k_scatter_flat(const int* __restrict__ src, const int* __restrict__ dst,
                               const float* __restrict__ h, const float* __restrict__ dis,
                               float* __restrict__ out, int e) {
    int i = blockIdx.x * blockDim.x + threadIdx.x;
    const int stride = gridDim.x * blockDim.x;
    for (; i < e; i += stride) {
        const int s = src[i], d = dst[i];
        atomicAdd(&out[d], dis[s] * dis[d] * h[s]);
    }
}

extern "C" void kernel_launch(void* const* d_in, const int* in_sizes, int n_in,
                              void* d_out, int out_size, void* d_ws, size_t ws_size,
                              hipStream_t stream) {
    const float* x  = (const float*)d_in[0];
    const int*   ei = (const int*)d_in[1];     // [2,E] int32: src row, dst row
    const float* W  = (const float*)d_in[2];
    const float* b  = (const float*)d_in[3];
    float* out = (float*)d_out;
    const int* src = ei;
    const int* dst = ei + GCN_E;

    float* h      = (float*)d_ws;                        // N
    float* dis    = h + GCN_N;                           // N
    float* g      = dis + GCN_N;                         // N
    int*   cursor = (int*)(g + GCN_N);                   // NBUCK
    int*   bpack  = cursor + NBUCK;                      // NBUCK*BCAP
    const size_t need = ((size_t)3 * GCN_N + NBUCK + (size_t)NBUCK * BCAP) * 4;

    if (ws_size >= need) {
        k_init<<<1, 512, 0, stream>>>(cursor);
        k_fused<<<NBLK, TB, 0, stream>>>(x, W, h, src, dst, cursor, bpack);
        k_deg_norm<<<NBUCK, 1024, 0, stream>>>(bpack, cursor, h, dis, g);
        k_scatter_bin<<<NBUCK, 1024, 0, stream>>>(bpack, cursor, g, dis, b, out);
    } else {
        float* hh  = (float*)d_ws;
        float* deg = hh + GCN_N;
        k_zero<<<512, 256, 0, stream>>>(deg, GCN_N);
        k_proj_sep<<<2048, 256, 0, stream>>>(x, W, hh, GCN_N);
        k_degree_flat<<<2048, 256, 0, stream>>>(dst, deg, GCN_E);
        k_norm_flat<<<(GCN_N + 255) / 256, 256, 0, stream>>>(hh, deg, out, b, GCN_N);
        k_scatter_flat<<<2048, 256, 0, stream>>>(src, dst, hh, deg, out, GCN_E);
    }
}